// Round 1
// baseline (189.331 us; speedup 1.0000x reference)
//
#include <hip/hip_runtime.h>
#include <math.h>

#define B 4
#define T 8
#define NF 8192
#define C 384
#define H 12
#define TOPK 32
#define D 32
#define STOT (T + NF)          // 8200
#define R (H * T)              // 96 score rows per batch
#define SCALE 0.17677669529663687f

// ---------------------------------------------------------------------------
// Kernel 1: per (b,t): q[o] = x[b,t,:] @ qs_w[t]  (384x384 matvec), then
// qk[h,c] = sum_d q[h*32+d] * kv_w[c, h*32+d]   -> qk_buf[(b*R + h*T + t)*C + c]
// ---------------------------------------------------------------------------
__global__ __launch_bounds__(256) void ta_qk_kernel(
    const float* __restrict__ x, const float* __restrict__ qs_w,
    const float* __restrict__ kv_w, float* __restrict__ qk_buf) {
  int b = blockIdx.x / T, t = blockIdx.x % T;
  int tid = threadIdx.x;
  __shared__ float xrow[C];
  __shared__ float q[C];
  if (tid < C / 4) {
    *reinterpret_cast<float4*>(xrow + tid * 4) =
        *reinterpret_cast<const float4*>(x + ((size_t)b * STOT + t) * C + tid * 4);
  }
  __syncthreads();
  for (int o = tid; o < C; o += 256) {
    float acc = 0.f;
    const float* w = qs_w + (size_t)t * C * C + o;
    for (int c = 0; c < C; ++c) acc += xrow[c] * w[(size_t)c * C];
    q[o] = acc;
  }
  __syncthreads();
  for (int u = tid; u < H * C; u += 256) {
    int h = u / C, c = u % C;
    const float* kw = kv_w + (size_t)c * (2 * C) + h * D;
    const float* qh = q + h * D;
    float acc = 0.f;
#pragma unroll
    for (int d4 = 0; d4 < D / 4; ++d4) {
      float4 kv4 = *reinterpret_cast<const float4*>(kw + d4 * 4);
      acc += qh[d4 * 4 + 0] * kv4.x + qh[d4 * 4 + 1] * kv4.y +
             qh[d4 * 4 + 2] * kv4.z + qh[d4 * 4 + 3] * kv4.w;
    }
    qk_buf[((size_t)b * R + (size_t)h * T + t) * C + c] = acc;
  }
}

// ---------------------------------------------------------------------------
// Kernel 2: scores[(b*R + r)*NF + n] = SCALE * feat[b,n,:] . qk[b,r,:]
// Tiled fp32 GEMM: per block 64 rows (n) x 96 cols (r), K=384 in chunks of 32.
// ---------------------------------------------------------------------------
#define TN 64
#define KC 32
__global__ __launch_bounds__(256) void ta_scores_kernel(
    const float* __restrict__ x, const float* __restrict__ qk_buf,
    float* __restrict__ scores) {
  int b = blockIdx.y;
  int n0 = blockIdx.x * TN;
  int tid = threadIdx.x;
  int tr = tid & 15;   // row group (consecutive lanes -> consecutive n)
  int tc = tid >> 4;   // col group 0..15
  __shared__ float fA[TN][KC + 4];
  __shared__ float fB[R][KC + 4];
  float acc[4][6];
#pragma unroll
  for (int i = 0; i < 4; ++i)
#pragma unroll
    for (int j = 0; j < 6; ++j) acc[i][j] = 0.f;

  const float* xb = x + ((size_t)b * STOT + T + n0) * C;
  const float* qb = qk_buf + (size_t)b * R * C;

  for (int c0 = 0; c0 < C; c0 += KC) {
#pragma unroll
    for (int s = 0; s < 2; ++s) {
      int v = tid + 256 * s;
      int row = v >> 3, c4 = (v & 7) * 4;
      float4 f = *reinterpret_cast<const float4*>(xb + (size_t)row * C + c0 + c4);
      *reinterpret_cast<float4*>(&fA[row][c4]) = f;
    }
#pragma unroll
    for (int s = 0; s < 3; ++s) {
      int v = tid + 256 * s;
      int row = v >> 3, c4 = (v & 7) * 4;
      float4 f = *reinterpret_cast<const float4*>(qb + (size_t)row * C + c0 + c4);
      *reinterpret_cast<float4*>(&fB[row][c4]) = f;
    }
    __syncthreads();
#pragma unroll
    for (int kk = 0; kk < KC; kk += 4) {
      float4 a4[4], b4[6];
#pragma unroll
      for (int i = 0; i < 4; ++i)
        a4[i] = *reinterpret_cast<const float4*>(&fA[tr + 16 * i][kk]);
#pragma unroll
      for (int j = 0; j < 6; ++j)
        b4[j] = *reinterpret_cast<const float4*>(&fB[tc + 16 * j][kk]);
#pragma unroll
      for (int i = 0; i < 4; ++i)
#pragma unroll
        for (int j = 0; j < 6; ++j) {
          acc[i][j] += a4[i].x * b4[j].x;
          acc[i][j] += a4[i].y * b4[j].y;
          acc[i][j] += a4[i].z * b4[j].z;
          acc[i][j] += a4[i].w * b4[j].w;
        }
    }
    __syncthreads();
  }
#pragma unroll
  for (int i = 0; i < 4; ++i) {
    int n = n0 + tr + 16 * i;
#pragma unroll
    for (int j = 0; j < 6; ++j) {
      int r = tc + 16 * j;
      scores[((size_t)b * R + r) * NF + n] = acc[i][j] * SCALE;
    }
  }
}

// ---------------------------------------------------------------------------
// Kernel 3: per score row (384 rows): top-32 via 32 x block-argmax on an LDS
// copy, then softmax; writes w[32] (fp32) and idx[32] (int).
// ---------------------------------------------------------------------------
__global__ __launch_bounds__(256) void ta_topk_kernel(
    const float* __restrict__ scores, float* __restrict__ w_buf,
    int* __restrict__ idx_buf) {
  int r = blockIdx.x;
  int tid = threadIdx.x;
  const float* row = scores + (size_t)r * NF;
  __shared__ float sv[NF];  // 32 KB
  __shared__ float wv[4];
  __shared__ int wi[4];
  __shared__ float selv[TOPK];
  __shared__ int seli[TOPK];
  __shared__ float eb[TOPK];
  __shared__ float esum;

  for (int i = tid * 4; i < NF; i += 1024) {
    *reinterpret_cast<float4*>(sv + i) = *reinterpret_cast<const float4*>(row + i);
  }
  __syncthreads();

  int lane = tid & 63, wid = tid >> 6;
  for (int it = 0; it < TOPK; ++it) {
    float bv = -1e30f;
    int bi = -1;
#pragma unroll
    for (int j = 0; j < NF / 256; ++j) {
      int i = tid + 256 * j;
      float v = sv[i];
      if (v > bv) { bv = v; bi = i; }
    }
#pragma unroll
    for (int off = 32; off >= 1; off >>= 1) {
      float ov = __shfl_down(bv, off);
      int oi = __shfl_down(bi, off);
      if (ov > bv) { bv = ov; bi = oi; }
    }
    if (lane == 0) { wv[wid] = bv; wi[wid] = bi; }
    __syncthreads();
    if (tid == 0) {
      float mv = wv[0]; int mi = wi[0];
      for (int g = 1; g < 4; ++g)
        if (wv[g] > mv) { mv = wv[g]; mi = wi[g]; }
      selv[it] = mv; seli[it] = mi;
      sv[mi] = -1e30f;
    }
    __syncthreads();
  }
  // softmax over the 32 selected values (selv[0] is the max)
  if (tid < TOPK) eb[tid] = expf(selv[tid] - selv[0]);
  __syncthreads();
  if (tid == 0) {
    float s = 0.f;
    for (int k = 0; k < TOPK; ++k) s += eb[k];
    esum = s;
  }
  __syncthreads();
  if (tid < TOPK) {
    w_buf[(size_t)r * TOPK + tid] = eb[tid] / esum;
    idx_buf[(size_t)r * TOPK + tid] = seli[tid];
  }
}

// ---------------------------------------------------------------------------
// Kernel 4: per (b,h,t): gather v at idx (computed on the fly from feature and
// the kv_w v-slice staged in LDS), attn_token slice, then token_out
// contribution: atomicAdd(out[b,t,:], att_slice @ Ew[t][hD:hD+D,:]).
// ---------------------------------------------------------------------------
__global__ __launch_bounds__(256) void ta_token_kernel(
    const float* __restrict__ x, const float* __restrict__ kv_w,
    const float* __restrict__ ew, const float* __restrict__ w_buf,
    const int* __restrict__ idx_buf, float* __restrict__ out) {
  int r = blockIdx.x;
  int t = r % T, h = (r / T) % H, b = r / (H * T);
  int tid = threadIdx.x;
  __shared__ float kvS[C * D];  // 48 KB: kvS[c*32+d] = kv_w[c, C + h*D + d]
  __shared__ float frow[C];
  __shared__ float part[8][D];
  __shared__ float att[D];
  __shared__ float wl[TOPK];
  __shared__ int il[TOPK];

  if (tid < TOPK) {
    wl[tid] = w_buf[(size_t)r * TOPK + tid];
    il[tid] = idx_buf[(size_t)r * TOPK + tid];
  }
  if (tid < D) att[tid] = 0.f;
  for (int e4 = tid; e4 < C * D / 4; e4 += 256) {
    int c = e4 >> 3, d4 = (e4 & 7) * 4;
    *reinterpret_cast<float4*>(kvS + c * D + d4) =
        *reinterpret_cast<const float4*>(kv_w + (size_t)c * (2 * C) + C + h * D + d4);
  }
  __syncthreads();

  int d = tid & 31, seg = tid >> 5;
  for (int k = 0; k < TOPK; ++k) {
    int n = il[k];
    const float* fr = x + ((size_t)b * STOT + T + n) * C;
    if (tid < C / 4)
      *reinterpret_cast<float4*>(frow + tid * 4) =
          *reinterpret_cast<const float4*>(fr + tid * 4);
    __syncthreads();
    float p = 0.f;
#pragma unroll
    for (int j = 0; j < C / 8; ++j) {  // 48 c-values per segment
      int c = seg * (C / 8) + j;
      p += frow[c] * kvS[c * D + d];
    }
    part[seg][d] = p;
    __syncthreads();
    if (tid < D) {
      float v = 0.f;
#pragma unroll
      for (int s = 0; s < 8; ++s) v += part[s][tid];
      att[tid] += wl[k] * v;
    }
    __syncthreads();
  }
  // token_out[b,t,o] += sum_d att[d] * ew[t, h*D+d, o]
  for (int o = tid; o < C; o += 256) {
    float acc = 0.f;
#pragma unroll
    for (int dd = 0; dd < D; ++dd)
      acc += att[dd] * ew[((size_t)t * C + h * D + dd) * C + o];
    atomicAdd(&out[((size_t)b * STOT + t) * C + o], acc);
  }
}

// ---------------------------------------------------------------------------
// Kernel 5: per (b,h,t): feature_out scatter.
// out[b, T+idx_k, o] += w_k * sum_d feat[b,idx_k,hD+d] * Ew[t, hD+d, o]
// Ew slice (32x384) staged in LDS; gathered feature slices (32x32) in LDS.
// ---------------------------------------------------------------------------
__global__ __launch_bounds__(256) void ta_scatter_kernel(
    const float* __restrict__ x, const float* __restrict__ ew,
    const float* __restrict__ w_buf, const int* __restrict__ idx_buf,
    float* __restrict__ out) {
  int r = blockIdx.x;
  int t = r % T, h = (r / T) % H, b = r / (H * T);
  int tid = threadIdx.x;
  __shared__ float ewS[D * C];       // 48 KB, contiguous copy of Ew[t, hD:hD+32, :]
  __shared__ float fr32[TOPK][D];    // 4 KB
  __shared__ float wl[TOPK];
  __shared__ int il[TOPK];

  if (tid < TOPK) {
    wl[tid] = w_buf[(size_t)r * TOPK + tid];
    il[tid] = idx_buf[(size_t)r * TOPK + tid];
  }
  const float* ewsrc = ew + (size_t)t * C * C + (size_t)h * D * C;
  for (int e4 = tid; e4 < D * C / 4; e4 += 256) {
    *reinterpret_cast<float4*>(ewS + e4 * 4) =
        *reinterpret_cast<const float4*>(ewsrc + e4 * 4);
  }
  __syncthreads();
  {
    int k0 = tid >> 5, d = tid & 31;
    for (int k = k0; k < TOPK; k += 8)
      fr32[k][d] = x[((size_t)b * STOT + T + il[k]) * C + h * D + d];
  }
  __syncthreads();
  for (int k = 0; k < TOPK; ++k) {
    float wk = wl[k];
    float* orow = out + ((size_t)b * STOT + T + il[k]) * C;
    for (int o = tid; o < C; o += 256) {
      float acc = 0.f;
#pragma unroll
      for (int dd = 0; dd < D; ++dd) acc += fr32[k][dd] * ewS[dd * C + o];
      atomicAdd(&orow[o], wk * acc);
    }
  }
}

// ---------------------------------------------------------------------------
extern "C" void kernel_launch(void* const* d_in, const int* in_sizes, int n_in,
                              void* d_out, int out_size, void* d_ws, size_t ws_size,
                              hipStream_t stream) {
  const float* x = (const float*)d_in[0];
  const float* qs_w = (const float*)d_in[1];
  const float* kv_w = (const float*)d_in[2];
  const float* ew = (const float*)d_in[3];
  float* out = (float*)d_out;

  // workspace layout (fp32): qk_buf [B*R*C], w_buf [B*R*TOPK], idx_buf [B*R*TOPK]
  float* qk_buf = (float*)d_ws;
  float* w_buf = (float*)((char*)d_ws + (size_t)B * R * C * 4);
  int* idx_buf = (int*)((char*)d_ws + (size_t)B * R * C * 4 + (size_t)B * R * TOPK * 4);

  // big score matrix (B*R*NF fp32 = 12.58M floats) staged inside d_out
  // (out_size = 12.595M floats), consumed by top-k before d_out is zeroed.
  float* scores = out;

  ta_qk_kernel<<<B * T, 256, 0, stream>>>(x, qs_w, kv_w, qk_buf);
  dim3 g2(NF / TN, B);
  ta_scores_kernel<<<g2, 256, 0, stream>>>(x, qk_buf, scores);
  ta_topk_kernel<<<B * R, 256, 0, stream>>>(scores, w_buf, idx_buf);
  hipMemsetAsync(d_out, 0, (size_t)out_size * sizeof(float), stream);
  ta_token_kernel<<<B * R, 256, 0, stream>>>(x, kv_w, ew, w_buf, idx_buf, out);
  ta_scatter_kernel<<<B * R, 256, 0, stream>>>(x, ew, w_buf, idx_buf, out);
}